// Round 7
// baseline (182.662 us; speedup 1.0000x reference)
//
#include <hip/hip_runtime.h>
#include <hip/hip_bf16.h>

// NT-Xent loss, BS=4096, D=256, TAU=0.5.
// R21 = R18 (82.87us best) + kfinal fused as phase 3 of kgemm, with the
// memory semantics done right this time.
// R19 (64us) / R20 (72us) post-mortem: agent-scope DATA accesses are the
// poison -- relaxed agent atomic stores bypass L2 write-combining (R20
// WRITE_SIZE 25MB for a 4MB P) and agent loads are uncached. The proven-
// correct cheap recipe: plain stores -> __syncthreads (vmcnt drain) ->
// agent ACQ_REL RMW on a counter (release emits L2 writeback); reader:
// acquire spin -> plain loads (acquire emits L2 invalidate; fill-poison
// lines were already invalidated at this dispatch's start-acquire). Each
// P line is written by exactly one wave (no cross-XCD line sharing).
// Fixes vs R19/R20: finalists = LAST 128 blocks (dispatched last, ~zero
// spin; non-finalists bump-and-exit -> no slot/deadlock hazard); counter
// spread over 32 cache-line-separated sub-counters (65 RMWs/line).
// Predict: -1 dispatch -1 gap -ramp = 3-6us -> 77-80us. Null => declare
// harness floor. absmax!=0 => revert to R18.
//
// znsw layout (fragment-native for mfma_scale_f32_16x16x128_f8f6f4,
// lane map: row = l&15, k = (l>>4)*32 + 0..31 per K=128 half):
//   16-row group rg (4096 B): piece pi (0..3) = h*2 + p (h = K-half,
//   p = 16-byte sub-piece): byte rg*4096 + pi*1024 + l*16 holds
//   row = rg*16 + (l&15), k = h*128 + (l>>4)*32 + p*16 + (0..15).
// A 128-row panel (8 rgs) = 32KB contiguous; staging stays 1:1 memcpy;
// all LDS/global fragment reads remain lane-contiguous 16B (conflict-free).

#define N_ROWS 8192
#define BSZ    4096
#define DIM    256
#define INV_TAU 2.0f
#define EPS_REF 1e-8f
#define COS_EPS 1e-8f
#define NG2     64                     // 128-row groups
#define NTILES  (NG2 * (NG2 + 1) / 2)  // 2080 triangular tiles
#define PH3BLK  128                    // finalist blocks (the last 128)
#define NCNT    32                     // sub-counters, one cacheline apart
#define LSTRIDE 260                    // padded floats per row in knorm LDS

typedef __attribute__((ext_vector_type(4))) float f32x4;
typedef __attribute__((ext_vector_type(8))) int   v8i;
typedef union { int4 x[2]; v8i v; } frag32;

// sum across each 16-lane group via DPP row_ror (VALU pipe, no LDS traffic)
__device__ __forceinline__ float red16(float x) {
    x += __int_as_float(__builtin_amdgcn_update_dpp(0, __float_as_int(x), 0x121, 0xf, 0xf, false));
    x += __int_as_float(__builtin_amdgcn_update_dpp(0, __float_as_int(x), 0x122, 0xf, 0xf, false));
    x += __int_as_float(__builtin_amdgcn_update_dpp(0, __float_as_int(x), 0x124, 0xf, 0xf, false));
    x += __int_as_float(__builtin_amdgcn_update_dpp(0, __float_as_int(x), 0x128, 0xf, 0xf, false));
    return x;
}

// ---------------- Kernel 1: normalize + fp8 quantize + MX-fragment swizzle --
__global__ __launch_bounds__(256) void knorm(const float* __restrict__ zi,
                                             const float* __restrict__ zj,
                                             unsigned char* __restrict__ znsw,
                                             unsigned int* __restrict__ cnt,
                                             float* __restrict__ out) {
    __shared__ float lds[16 * LSTRIDE];
    __shared__ float nrm[16];
    const int rg = blockIdx.x;     // 0..511: 16-row group
    const int t  = threadIdx.x;
    const int w  = t >> 6;
    const int l  = t & 63;
    const int row0 = rg * 16;
    if (rg == 0 && t == 0) out[0] = 0.f;           // kfused atomics run after us
    if (rg == 0 && t < NCNT) cnt[t * 16] = 0u;     // sub-counters (64B apart)

    // load + register norms: iteration s -> row 4s+w, cols l*4..l*4+3
    #pragma unroll
    for (int s = 0; s < 4; ++s) {
        const int row = s * 4 + w;
        const int r   = row0 + row;
        const float* src = (r < BSZ) ? zi + (size_t)r * DIM + l * 4
                                     : zj + (size_t)(r - BSZ) * DIM + l * 4;
        const float4 v = *(const float4*)src;
        *(float4*)&lds[row * LSTRIDE + l * 4] = v;
        float ss = v.x*v.x + v.y*v.y + v.z*v.z + v.w*v.w;
        #pragma unroll
        for (int off = 32; off >= 1; off >>= 1) ss += __shfl_xor(ss, off);
        if (l == 0) nrm[row] = 1.0f / fmaxf(sqrtf(ss), COS_EPS);
    }
    __syncthreads();

    // quantize: thread t -> piece pi = t>>6 (h = pi>>1, p = pi&1), lane fl.
    // 16 consecutive k starting at h*128 + (fl>>4)*32 + p*16, row fl&15.
    const int pi = t >> 6, fl = t & 63;
    const int h = pi >> 1, p = pi & 1;
    const int r16 = fl & 15, q = fl >> 4;
    const int k0 = h * 128 + q * 32 + p * 16;
    const float inv = nrm[r16];
    float f[16];
    #pragma unroll
    for (int j = 0; j < 16; ++j) f[j] = lds[r16 * LSTRIDE + k0 + j] * inv;
    int wd[4];
    #pragma unroll
    for (int g = 0; g < 4; ++g) {
        int a = 0;
        a = __builtin_amdgcn_cvt_pk_fp8_f32(f[g*4+0], f[g*4+1], a, false);
        a = __builtin_amdgcn_cvt_pk_fp8_f32(f[g*4+2], f[g*4+3], a, true);
        wd[g] = a;
    }
    *(int4*)(znsw + (size_t)rg * 4096 + pi * 1024 + fl * 16) =
        make_int4(wd[0], wd[1], wd[2], wd[3]);
}

// ---------------- Kernel 2: triangular Gram + fused phase-3 loss -----------
__global__ __launch_bounds__(256, 3) void kfused(const unsigned char* __restrict__ znsw,
                                                 float* __restrict__ P,
                                                 float* __restrict__ selfdot,
                                                 float* __restrict__ pairdot,
                                                 unsigned int* __restrict__ cnt,
                                                 float* __restrict__ out) {
    __shared__ __align__(16) unsigned char pan[32768];   // A panel (all K)
    __shared__ float wsum[4][64];
    const int w = threadIdx.x >> 6;
    const int l = threadIdx.x & 63;

    // triangular decode over NG2=64: S(G) = G*(129-G)/2
    const int t = blockIdx.x;
    int Gi = (int)((129.0f - sqrtf(16641.0f - 8.0f * (float)t)) * 0.5f);
    while ((Gi + 1) * (129 - (Gi + 1)) / 2 <= t) ++Gi;
    while (Gi * (129 - Gi) / 2 > t) --Gi;
    const int Gj = Gi + (t - Gi * (129 - Gi) / 2);

    // stage A panel (32KB): 1:1 contiguous copy, 8 issues/thread
    const char* srcA = (const char*)znsw + (size_t)Gi * 32768;
    #pragma unroll
    for (int sub = 0; sub < 8; ++sub) {
        const int off = sub * 4096 + w * 1024;
        __builtin_amdgcn_global_load_lds(
            (const __attribute__((address_space(1))) void*)(srcA + off + l * 16),
            (__attribute__((address_space(3))) void*)(&pan[off]), 16, 0, 0);
    }

    // quadrant: rows (w>>1)*64 of A, cols (w&1)*64 of B
    const int rh = w >> 1, ch = w & 1;
    // B fragment global base for (nt, h, p): bbase + nt*4096 + h*2048 + p*1024
    const char* bbase = (const char*)znsw + (size_t)Gj * 32768 + ch * 16384 + l * 16;

    // prefetch h=0 B fragments before the barrier (drain together with A)
    frag32 B[4];
    #pragma unroll
    for (int nt = 0; nt < 4; ++nt) {
        B[nt].x[0] = *(const int4*)(bbase + nt * 4096);
        B[nt].x[1] = *(const int4*)(bbase + nt * 4096 + 1024);
    }

    f32x4 acc[4][4];
    #pragma unroll
    for (int mt = 0; mt < 4; ++mt)
        #pragma unroll
        for (int nt = 0; nt < 4; ++nt)
            acc[mt][nt] = (f32x4){0.f, 0.f, 0.f, 0.f};

    __syncthreads();   // A staged; h=0 B in flight drained here too

    #pragma unroll
    for (int h = 0; h < 2; ++h) {
        if (h == 1) {   // reload same buffer with second K-half
            #pragma unroll
            for (int nt = 0; nt < 4; ++nt) {
                B[nt].x[0] = *(const int4*)(bbase + nt * 4096 + 2048);
                B[nt].x[1] = *(const int4*)(bbase + nt * 4096 + 3072);
            }
        }
        #pragma unroll
        for (int mt = 0; mt < 4; ++mt) {
            frag32 A;   // per-mt LDS read: 8 VGPRs live instead of 32
            const char* ap = (const char*)&pan[(rh * 4 + mt) * 4096 + h * 2048] + l * 16;
            A.x[0] = *(const int4*)(ap);
            A.x[1] = *(const int4*)(ap + 1024);
            #pragma unroll
            for (int nt = 0; nt < 4; ++nt)
                acc[mt][nt] = __builtin_amdgcn_mfma_scale_f32_16x16x128_f8f6f4(
                    A.v, B[nt].v, acc[mt][nt],
                    0, 0,                     // cbsz=0 (fp8 e4m3), blgp=0 (fp8)
                    0, 0x7f7f7f7f,            // scale_a opsel, e8m0 1.0
                    0, 0x7f7f7f7f);           // scale_b opsel, e8m0 1.0
        }
    }

    // ---- wave-local epilogue (C/D layout: col = l&15, row = (l>>4)*4+reg) ----
    // All data uses PLAIN stores; visibility comes from the release below.
    const int c = l & 15, q = l >> 4;
    const int rsel = c - 4 * q;
    const bool vld = (rsel >= 0) && (rsel < 4);

    if ((Gi == Gj || Gj == Gi + 32) && rh == ch) {
        float dv[4];
        #pragma unroll
        for (int mt = 0; mt < 4; ++mt) {
            float d = acc[mt][mt][0];
            #pragma unroll
            for (int r = 1; r < 4; ++r)
                if (rsel == r) d = acc[mt][mt][r];
            dv[mt] = d;
        }
        if (vld) {
            float* dst = (Gi == Gj) ? selfdot : pairdot;
            #pragma unroll
            for (int mt = 0; mt < 4; ++mt)
                dst[Gi * 128 + rh * 64 + mt * 16 + c] = dv[mt];
        }
    }

    #pragma unroll
    for (int mt = 0; mt < 4; ++mt)
        #pragma unroll
        for (int nt = 0; nt < 4; ++nt)
            #pragma unroll
            for (int r = 0; r < 4; ++r)
                acc[mt][nt][r] = __expf(acc[mt][nt][r] * INV_TAU);

    // row sums (DPP reduce across 16 col lanes) -> P[Gj*2+ch][...]
    float rs[4][4];
    #pragma unroll
    for (int mt = 0; mt < 4; ++mt)
        #pragma unroll
        for (int r = 0; r < 4; ++r)
            rs[mt][r] = red16(acc[mt][0][r] + acc[mt][1][r] + acc[mt][2][r] + acc[mt][3][r]);
    if (c == 0) {
        #pragma unroll
        for (int mt = 0; mt < 4; ++mt)
            *(f32x4*)&P[(size_t)(Gj * 2 + ch) * N_ROWS + Gi * 128 + rh * 64 + mt * 16 + q * 4] =
                (f32x4){rs[mt][0], rs[mt][1], rs[mt][2], rs[mt][3]};
    }

    // col sums (strictly-upper blocks) -> P[Gi*2+rh][Gj*128 + ...]
    if (Gi != Gj) {
        float cs[4];
        #pragma unroll
        for (int nt = 0; nt < 4; ++nt) {
            float s = 0.f;
            #pragma unroll
            for (int mt = 0; mt < 4; ++mt)
                #pragma unroll
                for (int r = 0; r < 4; ++r)
                    s += acc[mt][nt][r];
            s += __shfl_xor(s, 16);
            s += __shfl_xor(s, 32);
            cs[nt] = s;
        }
        if (q == 0) {
            #pragma unroll
            for (int nt = 0; nt < 4; ++nt)
                P[(size_t)(Gi * 2 + rh) * N_ROWS + Gj * 128 + ch * 64 + nt * 16 + c] = cs[nt];
        }
    }

    // ---- arrival: plain stores drained at syncthreads; release via agent
    // ACQ_REL RMW on a striped sub-counter (65 RMWs per cacheline).
    __syncthreads();
    if (threadIdx.x == 0)
        __hip_atomic_fetch_add(&cnt[(blockIdx.x & (NCNT - 1)) * 16], 1u,
                               __ATOMIC_ACQ_REL, __HIP_MEMORY_SCOPE_AGENT);
    if (blockIdx.x < NTILES - PH3BLK) return;

    // ---- finalists (last 128 blocks, dispatched last -> ~zero spin) ----
    if (threadIdx.x == 0) {
        unsigned int total;
        do {
            total = 0;
            #pragma unroll
            for (int i = 0; i < NCNT; ++i)
                total += __hip_atomic_load(&cnt[i * 16], __ATOMIC_ACQUIRE,
                                           __HIP_MEMORY_SCOPE_AGENT);
            if (total < NTILES) __builtin_amdgcn_s_sleep(1);
        } while (total < NTILES);
    }
    __syncthreads();   // acquire (L2 invalidated) visible to whole block

    // phase 3: old kfinal body; plain loads are now coherent.
    const int fb  = blockIdx.x - (NTILES - PH3BLK);
    const int row = fb * 64 + l;
    float s = 0.f;
    #pragma unroll
    for (int st = 0; st < 32; ++st)
        s += P[(size_t)(w * 32 + st) * N_ROWS + row];
    wsum[w][l] = s;
    __syncthreads();
    if (w == 0) {
        const float tot = wsum[0][l] + wsum[1][l] + wsum[2][l] + wsum[3][l];
        const float selfe = __expf(selfdot[row] * INV_TAU);
        const float pd    = pairdot[(row < BSZ) ? row : row - BSZ];
        float loss = logf(tot - selfe + EPS_REF) - pd * INV_TAU;
        #pragma unroll
        for (int off = 32; off >= 1; off >>= 1) loss += __shfl_xor(loss, off);
        if (l == 0) atomicAdd(out, loss * (1.0f / (float)N_ROWS));
    }
}

extern "C" void kernel_launch(void* const* d_in, const int* in_sizes, int n_in,
                              void* d_out, int out_size, void* d_ws, size_t ws_size,
                              hipStream_t stream) {
    const float* zi = (const float*)d_in[0];
    const float* zj = (const float*)d_in[1];
    float* out = (float*)d_out;

    char* ws = (char*)d_ws;
    unsigned char* znsw = (unsigned char*)ws;                          // 2 MB
    float* P       = (float*)(ws + 2 * 1024 * 1024);                   // 4 MB
    float* selfdot = (float*)(ws + 6 * 1024 * 1024);                   // 32 KB
    float* pairdot = (float*)(ws + 6 * 1024 * 1024 + 32 * 1024);       // 16 KB
    unsigned int* cnt = (unsigned int*)(ws + 6 * 1024 * 1024 + 48 * 1024); // 2 KB

    knorm <<<N_ROWS / 16, 256, 0, stream>>>(zi, zj, znsw, cnt, out);
    kfused<<<NTILES, 256, 0, stream>>>(znsw, P, selfdot, pairdot, cnt, out);
}

// Round 9
// 86.873 us; speedup vs baseline: 2.1026x; 2.1026x over previous
//
#include <hip/hip_runtime.h>
#include <hip/hip_bf16.h>

// NT-Xent loss, BS=4096, D=256, TAU=0.5.
// R23 = R22 resubmitted verbatim (R8 bench was a container flake: no
// pytest/compile/rocprof output). R22 = R18 (82.87 best) + P-halving +
// kfinal reshape. Fusion arc (R19-R21) is dead: per-block agent-scope
// release/acquire = per-XCD L2 wb/inv (~0.1-0.3us serialized); R21's
// acquire-spin storm starved the GEMM (127us, HBM 117GB/s). Kernel
// boundaries are the cheap coherence op. Changes vs R18:
//  (1) kgemm epilogue: ch/rh wave-pairs combined via 2KB LDS -> P2[64][8192]
//      (2MB, was 4MB) written as two coalesced 512B wave-stores per block
//      (was ~40 scattered per-lane stores). Writer uniqueness: strip=Gj for
//      row-sums (tile (g,s), s>=g), strip=Gi for col-sums (tile (s,g), s<g).
//  (2) kfinal: 512 blocks x 16 rows (2 blocks/CU, was 0.5), 4 loads/thread
//      (was 32), LDS+shuffle reduce.
// Predict 80-82us; null => controllable remainder is gaps/fixed overhead,
// declare floor next round.
//
// znsw layout (fragment-native for mfma_scale_f32_16x16x128_f8f6f4,
// lane map: row = l&15, k = (l>>4)*32 + 0..31 per K=128 half):
//   16-row group rg (4096 B): piece pi (0..3) = h*2 + p (h = K-half,
//   p = 16-byte sub-piece): byte rg*4096 + pi*1024 + l*16 holds
//   row = rg*16 + (l&15), k = h*128 + (l>>4)*32 + p*16 + (0..15).
// A 128-row panel (8 rgs) = 32KB contiguous; staging stays 1:1 memcpy;
// all LDS/global fragment reads remain lane-contiguous 16B (conflict-free).

#define N_ROWS 8192
#define BSZ    4096
#define DIM    256
#define INV_TAU 2.0f
#define EPS_REF 1e-8f
#define COS_EPS 1e-8f
#define NG2     64                     // 128-row groups
#define NTILES  (NG2 * (NG2 + 1) / 2)  // 2080 triangular tiles
#define LSTRIDE 260                    // padded floats per row in knorm LDS

typedef __attribute__((ext_vector_type(4))) float f32x4;
typedef __attribute__((ext_vector_type(8))) int   v8i;
typedef union { int4 x[2]; v8i v; } frag32;

// sum across each 16-lane group via DPP row_ror (VALU pipe, no LDS traffic)
__device__ __forceinline__ float red16(float x) {
    x += __int_as_float(__builtin_amdgcn_update_dpp(0, __float_as_int(x), 0x121, 0xf, 0xf, false));
    x += __int_as_float(__builtin_amdgcn_update_dpp(0, __float_as_int(x), 0x122, 0xf, 0xf, false));
    x += __int_as_float(__builtin_amdgcn_update_dpp(0, __float_as_int(x), 0x124, 0xf, 0xf, false));
    x += __int_as_float(__builtin_amdgcn_update_dpp(0, __float_as_int(x), 0x128, 0xf, 0xf, false));
    return x;
}

// ---------------- Kernel 1: normalize + fp8 quantize + MX-fragment swizzle --
__global__ __launch_bounds__(256) void knorm(const float* __restrict__ zi,
                                             const float* __restrict__ zj,
                                             unsigned char* __restrict__ znsw,
                                             float* __restrict__ out) {
    __shared__ float lds[16 * LSTRIDE];
    __shared__ float nrm[16];
    const int rg = blockIdx.x;     // 0..511: 16-row group
    const int t  = threadIdx.x;
    const int w  = t >> 6;
    const int l  = t & 63;
    const int row0 = rg * 16;
    if (rg == 0 && t == 0) out[0] = 0.f;    // kfinal atomics run after us

    // load + register norms: iteration s -> row 4s+w, cols l*4..l*4+3
    #pragma unroll
    for (int s = 0; s < 4; ++s) {
        const int row = s * 4 + w;
        const int r   = row0 + row;
        const float* src = (r < BSZ) ? zi + (size_t)r * DIM + l * 4
                                     : zj + (size_t)(r - BSZ) * DIM + l * 4;
        const float4 v = *(const float4*)src;
        *(float4*)&lds[row * LSTRIDE + l * 4] = v;
        float ss = v.x*v.x + v.y*v.y + v.z*v.z + v.w*v.w;
        #pragma unroll
        for (int off = 32; off >= 1; off >>= 1) ss += __shfl_xor(ss, off);
        if (l == 0) nrm[row] = 1.0f / fmaxf(sqrtf(ss), COS_EPS);
    }
    __syncthreads();

    // quantize: thread t -> piece pi = t>>6 (h = pi>>1, p = pi&1), lane fl.
    // 16 consecutive k starting at h*128 + (fl>>4)*32 + p*16, row fl&15.
    const int pi = t >> 6, fl = t & 63;
    const int h = pi >> 1, p = pi & 1;
    const int r16 = fl & 15, q = fl >> 4;
    const int k0 = h * 128 + q * 32 + p * 16;
    const float inv = nrm[r16];
    float f[16];
    #pragma unroll
    for (int j = 0; j < 16; ++j) f[j] = lds[r16 * LSTRIDE + k0 + j] * inv;
    int wd[4];
    #pragma unroll
    for (int g = 0; g < 4; ++g) {
        int a = 0;
        a = __builtin_amdgcn_cvt_pk_fp8_f32(f[g*4+0], f[g*4+1], a, false);
        a = __builtin_amdgcn_cvt_pk_fp8_f32(f[g*4+2], f[g*4+3], a, true);
        wd[g] = a;
    }
    *(int4*)(znsw + (size_t)rg * 4096 + pi * 1024 + fl * 16) =
        make_int4(wd[0], wd[1], wd[2], wd[3]);
}

// ---------------- Kernel 2: triangular Gram; A staged, B direct, MX MFMA ----
__global__ __launch_bounds__(256, 3) void kgemm(const unsigned char* __restrict__ znsw,
                                                float* __restrict__ P2,
                                                float* __restrict__ selfdot,
                                                float* __restrict__ pairdot) {
    __shared__ __align__(16) unsigned char pan[32768];   // A panel (all K)
    __shared__ float rbuf[2][128];                       // row-sum combine (ch)
    __shared__ float cbuf[2][128];                       // col-sum combine (rh)
    const int w = threadIdx.x >> 6;
    const int l = threadIdx.x & 63;

    // triangular decode over NG2=64: S(G) = G*(129-G)/2
    const int t = blockIdx.x;
    int Gi = (int)((129.0f - sqrtf(16641.0f - 8.0f * (float)t)) * 0.5f);
    while ((Gi + 1) * (129 - (Gi + 1)) / 2 <= t) ++Gi;
    while (Gi * (129 - Gi) / 2 > t) --Gi;
    const int Gj = Gi + (t - Gi * (129 - Gi) / 2);

    // stage A panel (32KB): 1:1 contiguous copy, 8 issues/thread
    const char* srcA = (const char*)znsw + (size_t)Gi * 32768;
    #pragma unroll
    for (int sub = 0; sub < 8; ++sub) {
        const int off = sub * 4096 + w * 1024;
        __builtin_amdgcn_global_load_lds(
            (const __attribute__((address_space(1))) void*)(srcA + off + l * 16),
            (__attribute__((address_space(3))) void*)(&pan[off]), 16, 0, 0);
    }

    // quadrant: rows (w>>1)*64 of A, cols (w&1)*64 of B
    const int rh = w >> 1, ch = w & 1;
    // B fragment global base for (nt, h, p): bbase + nt*4096 + h*2048 + p*1024
    const char* bbase = (const char*)znsw + (size_t)Gj * 32768 + ch * 16384 + l * 16;

    // prefetch h=0 B fragments before the barrier (drain together with A)
    frag32 B[4];
    #pragma unroll
    for (int nt = 0; nt < 4; ++nt) {
        B[nt].x[0] = *(const int4*)(bbase + nt * 4096);
        B[nt].x[1] = *(const int4*)(bbase + nt * 4096 + 1024);
    }

    f32x4 acc[4][4];
    #pragma unroll
    for (int mt = 0; mt < 4; ++mt)
        #pragma unroll
        for (int nt = 0; nt < 4; ++nt)
            acc[mt][nt] = (f32x4){0.f, 0.f, 0.f, 0.f};

    __syncthreads();   // A staged; h=0 B in flight drained here too

    #pragma unroll
    for (int h = 0; h < 2; ++h) {
        if (h == 1) {   // reload same buffer with second K-half
            #pragma unroll
            for (int nt = 0; nt < 4; ++nt) {
                B[nt].x[0] = *(const int4*)(bbase + nt * 4096 + 2048);
                B[nt].x[1] = *(const int4*)(bbase + nt * 4096 + 3072);
            }
        }
        #pragma unroll
        for (int mt = 0; mt < 4; ++mt) {
            frag32 A;   // per-mt LDS read: 8 VGPRs live instead of 32
            const char* ap = (const char*)&pan[(rh * 4 + mt) * 4096 + h * 2048] + l * 16;
            A.x[0] = *(const int4*)(ap);
            A.x[1] = *(const int4*)(ap + 1024);
            #pragma unroll
            for (int nt = 0; nt < 4; ++nt)
                acc[mt][nt] = __builtin_amdgcn_mfma_scale_f32_16x16x128_f8f6f4(
                    A.v, B[nt].v, acc[mt][nt],
                    0, 0,                     // cbsz=0 (fp8 e4m3), blgp=0 (fp8)
                    0, 0x7f7f7f7f,            // scale_a opsel, e8m0 1.0
                    0, 0x7f7f7f7f);           // scale_b opsel, e8m0 1.0
        }
    }

    // ---- wave-local epilogue (C/D layout: col = l&15, row = (l>>4)*4+reg) ----
    const int c = l & 15, q = l >> 4;
    const int rsel = c - 4 * q;
    const bool vld = (rsel >= 0) && (rsel < 4);

    // self/pair diagonals live in quadrants with rh==ch
    if ((Gi == Gj || Gj == Gi + 32) && rh == ch) {
        float dv[4];
        #pragma unroll
        for (int mt = 0; mt < 4; ++mt) {
            float d = acc[mt][mt][0];
            #pragma unroll
            for (int r = 1; r < 4; ++r)
                if (rsel == r) d = acc[mt][mt][r];
            dv[mt] = d;
        }
        if (vld) {
            float* dst = (Gi == Gj) ? selfdot : pairdot;
            #pragma unroll
            for (int mt = 0; mt < 4; ++mt)
                dst[Gi * 128 + rh * 64 + mt * 16 + c] = dv[mt];
        }
    }

    #pragma unroll
    for (int mt = 0; mt < 4; ++mt)
        #pragma unroll
        for (int nt = 0; nt < 4; ++nt)
            #pragma unroll
            for (int r = 0; r < 4; ++r)
                acc[mt][nt][r] = __expf(acc[mt][nt][r] * INV_TAU);

    // row sums (DPP reduce across 16 col lanes): wave (rh,ch) covers
    // rows rh*64+mt*16+q*4+r over the 64-col half ch -> rbuf[ch][...]
    float rs[4][4];
    #pragma unroll
    for (int mt = 0; mt < 4; ++mt)
        #pragma unroll
        for (int r = 0; r < 4; ++r)
            rs[mt][r] = red16(acc[mt][0][r] + acc[mt][1][r] + acc[mt][2][r] + acc[mt][3][r]);
    if (c == 0) {
        #pragma unroll
        for (int mt = 0; mt < 4; ++mt)
            #pragma unroll
            for (int r = 0; r < 4; ++r)
                rbuf[ch][rh * 64 + mt * 16 + q * 4 + r] = rs[mt][r];
    }

    // col sums over this wave's 64 A-rows (rh half) per B-col -> cbuf[rh][...]
    if (Gi != Gj) {
        float cs[4];
        #pragma unroll
        for (int nt = 0; nt < 4; ++nt) {
            float s = 0.f;
            #pragma unroll
            for (int mt = 0; mt < 4; ++mt)
                #pragma unroll
                for (int r = 0; r < 4; ++r)
                    s += acc[mt][nt][r];
            s += __shfl_xor(s, 16);
            s += __shfl_xor(s, 32);
            cs[nt] = s;
        }
        if (q == 0) {
            #pragma unroll
            for (int nt = 0; nt < 4; ++nt)
                cbuf[rh][ch * 64 + nt * 16 + c] = cs[nt];
        }
    }

    __syncthreads();   // combine halves, write coalesced
    const int tt = threadIdx.x;
    if (tt < 128) {
        // strip Gj: contributions to rows of group Gi from col-group Gj
        P2[(size_t)Gj * N_ROWS + Gi * 128 + tt] = rbuf[0][tt] + rbuf[1][tt];
    } else if (Gi != Gj) {
        // strip Gi: contributions to rows of group Gj from row-group Gi
        const int x = tt - 128;
        P2[(size_t)Gi * N_ROWS + Gj * 128 + x] = cbuf[0][x] + cbuf[1][x];
    }
}

// ---------------- Kernel 3: per-row loss, 512 blocks x 16 rows --------------
__global__ __launch_bounds__(256) void kfinal(const float* __restrict__ P2,
                                              const float* __restrict__ selfdot,
                                              const float* __restrict__ pairdot,
                                              float* __restrict__ out) {
    __shared__ float red[16][17];
    const int t = threadIdx.x;
    const int r16 = t & 15;            // row within block
    const int k   = t >> 4;            // strip phase (0..15)
    const int row = blockIdx.x * 16 + r16;
    float s = 0.f;
    #pragma unroll
    for (int j = 0; j < 4; ++j)
        s += P2[(size_t)(k + 16 * j) * N_ROWS + row];
    red[r16][k] = s;
    __syncthreads();
    if (t < 64) {
        const int rr = t & 15, kk = t >> 4;   // kk = 0..3
        float s2 = red[rr][kk] + red[rr][kk + 4] + red[rr][kk + 8] + red[rr][kk + 12];
        s2 += __shfl_xor(s2, 16);
        s2 += __shfl_xor(s2, 32);             // full row total on all 64 lanes
        if (t < 16) {
            const int myrow = blockIdx.x * 16 + t;
            const float selfe = __expf(selfdot[myrow] * INV_TAU);
            const float pd    = pairdot[(myrow < BSZ) ? myrow : myrow - BSZ];
            float loss = logf(s2 - selfe + EPS_REF) - pd * INV_TAU;
            loss = red16(loss);               // sum of the block's 16 rows
            if (t == 0) atomicAdd(out, loss * (1.0f / (float)N_ROWS));
        }
    }
}

extern "C" void kernel_launch(void* const* d_in, const int* in_sizes, int n_in,
                              void* d_out, int out_size, void* d_ws, size_t ws_size,
                              hipStream_t stream) {
    const float* zi = (const float*)d_in[0];
    const float* zj = (const float*)d_in[1];
    float* out = (float*)d_out;

    char* ws = (char*)d_ws;
    unsigned char* znsw = (unsigned char*)ws;                       // 2 MB
    float* P2      = (float*)(ws + 2 * 1024 * 1024);                // 2 MB
    float* selfdot = (float*)(ws + 4 * 1024 * 1024);                // 32 KB
    float* pairdot = (float*)(ws + 4 * 1024 * 1024 + 32 * 1024);    // 16 KB

    knorm <<<N_ROWS / 16, 256, 0, stream>>>(zi, zj, znsw, out);
    kgemm <<<NTILES, 256, 0, stream>>>(znsw, P2, selfdot, pairdot);
    kfinal<<<N_ROWS / 16, 256, 0, stream>>>(P2, selfdot, pairdot, out);
}

// Round 10
// 83.043 us; speedup vs baseline: 2.1996x; 1.0461x over previous
//
#include <hip/hip_runtime.h>
#include <hip/hip_bf16.h>

// NT-Xent loss, BS=4096, D=256, TAU=0.5.
// R24 = REVERT to R18 (82.87us, session best) as the final kernel.
// Nine-round scoreboard on the ~27us controllable pipeline (of 83 total;
// 42us harness poison-fill at the write roofline + ~14us fixed replay):
//   MFMA rate x2 (R14): null.  Clean 3 blocks/CU (R18): null.
//   L2 traffic -37% (R17): -3 (serialization).
//   Intra-kernel fusion (R19/20/21): -34/-46/-100 -- agent-scope
//     release/acquire costs per-XCD L2 wb/inv, 25-100x a kernel boundary.
//   Epilogue coalesce + kfinal reshape (R22/23): -4 (added barrier).
// Ruled out by arithmetic: XCD swizzle (znsw = 2MB, L2-resident per XCD
// already); knorm fusion (global dependency). Conclusion: R18 is at the
// practical floor; remaining time is harness-fixed.
//
// znsw layout (fragment-native for mfma_scale_f32_16x16x128_f8f6f4,
// lane map: row = l&15, k = (l>>4)*32 + 0..31 per K=128 half):
//   16-row group rg (4096 B): piece pi (0..3) = h*2 + p (h = K-half,
//   p = 16-byte sub-piece): byte rg*4096 + pi*1024 + l*16 holds
//   row = rg*16 + (l&15), k = h*128 + (l>>4)*32 + p*16 + (0..15).
// A 128-row panel (8 rgs) = 32KB contiguous; staging stays 1:1 memcpy;
// all LDS/global fragment reads remain lane-contiguous 16B (conflict-free).

#define N_ROWS 8192
#define BSZ    4096
#define DIM    256
#define INV_TAU 2.0f
#define EPS_REF 1e-8f
#define COS_EPS 1e-8f
#define NG2     64                     // 128-row groups
#define NTILES  (NG2 * (NG2 + 1) / 2)  // 2080 triangular tiles
#define LSTRIDE 260                    // padded floats per row in knorm LDS

typedef __attribute__((ext_vector_type(4))) float f32x4;
typedef __attribute__((ext_vector_type(8))) int   v8i;
typedef union { int4 x[2]; v8i v; } frag32;

// sum across each 16-lane group via DPP row_ror (VALU pipe, no LDS traffic)
__device__ __forceinline__ float red16(float x) {
    x += __int_as_float(__builtin_amdgcn_update_dpp(0, __float_as_int(x), 0x121, 0xf, 0xf, false));
    x += __int_as_float(__builtin_amdgcn_update_dpp(0, __float_as_int(x), 0x122, 0xf, 0xf, false));
    x += __int_as_float(__builtin_amdgcn_update_dpp(0, __float_as_int(x), 0x124, 0xf, 0xf, false));
    x += __int_as_float(__builtin_amdgcn_update_dpp(0, __float_as_int(x), 0x128, 0xf, 0xf, false));
    return x;
}

// ---------------- Kernel 1: normalize + fp8 quantize + MX-fragment swizzle --
__global__ __launch_bounds__(256) void knorm(const float* __restrict__ zi,
                                             const float* __restrict__ zj,
                                             unsigned char* __restrict__ znsw,
                                             float* __restrict__ out) {
    __shared__ float lds[16 * LSTRIDE];
    __shared__ float nrm[16];
    const int rg = blockIdx.x;     // 0..511: 16-row group
    const int t  = threadIdx.x;
    const int w  = t >> 6;
    const int l  = t & 63;
    const int row0 = rg * 16;
    if (rg == 0 && t == 0) out[0] = 0.f;    // kfinal atomics run after us

    // load + register norms: iteration s -> row 4s+w, cols l*4..l*4+3
    #pragma unroll
    for (int s = 0; s < 4; ++s) {
        const int row = s * 4 + w;
        const int r   = row0 + row;
        const float* src = (r < BSZ) ? zi + (size_t)r * DIM + l * 4
                                     : zj + (size_t)(r - BSZ) * DIM + l * 4;
        const float4 v = *(const float4*)src;
        *(float4*)&lds[row * LSTRIDE + l * 4] = v;
        float ss = v.x*v.x + v.y*v.y + v.z*v.z + v.w*v.w;
        #pragma unroll
        for (int off = 32; off >= 1; off >>= 1) ss += __shfl_xor(ss, off);
        if (l == 0) nrm[row] = 1.0f / fmaxf(sqrtf(ss), COS_EPS);
    }
    __syncthreads();

    // quantize: thread t -> piece pi = t>>6 (h = pi>>1, p = pi&1), lane fl.
    // 16 consecutive k starting at h*128 + (fl>>4)*32 + p*16, row fl&15.
    const int pi = t >> 6, fl = t & 63;
    const int h = pi >> 1, p = pi & 1;
    const int r16 = fl & 15, q = fl >> 4;
    const int k0 = h * 128 + q * 32 + p * 16;
    const float inv = nrm[r16];
    float f[16];
    #pragma unroll
    for (int j = 0; j < 16; ++j) f[j] = lds[r16 * LSTRIDE + k0 + j] * inv;
    int wd[4];
    #pragma unroll
    for (int g = 0; g < 4; ++g) {
        int a = 0;
        a = __builtin_amdgcn_cvt_pk_fp8_f32(f[g*4+0], f[g*4+1], a, false);
        a = __builtin_amdgcn_cvt_pk_fp8_f32(f[g*4+2], f[g*4+3], a, true);
        wd[g] = a;
    }
    *(int4*)(znsw + (size_t)rg * 4096 + pi * 1024 + fl * 16) =
        make_int4(wd[0], wd[1], wd[2], wd[3]);
}

// ---------------- Kernel 2: triangular Gram; A staged, B direct, MX MFMA ----
__global__ __launch_bounds__(256, 3) void kgemm(const unsigned char* __restrict__ znsw,
                                                float* __restrict__ P,
                                                float* __restrict__ selfdot,
                                                float* __restrict__ pairdot) {
    __shared__ __align__(16) unsigned char pan[32768];   // A panel (all K)
    const int w = threadIdx.x >> 6;
    const int l = threadIdx.x & 63;

    // triangular decode over NG2=64: S(G) = G*(129-G)/2
    const int t = blockIdx.x;
    int Gi = (int)((129.0f - sqrtf(16641.0f - 8.0f * (float)t)) * 0.5f);
    while ((Gi + 1) * (129 - (Gi + 1)) / 2 <= t) ++Gi;
    while (Gi * (129 - Gi) / 2 > t) --Gi;
    const int Gj = Gi + (t - Gi * (129 - Gi) / 2);

    // stage A panel (32KB): 1:1 contiguous copy, 8 issues/thread
    const char* srcA = (const char*)znsw + (size_t)Gi * 32768;
    #pragma unroll
    for (int sub = 0; sub < 8; ++sub) {
        const int off = sub * 4096 + w * 1024;
        __builtin_amdgcn_global_load_lds(
            (const __attribute__((address_space(1))) void*)(srcA + off + l * 16),
            (__attribute__((address_space(3))) void*)(&pan[off]), 16, 0, 0);
    }

    // quadrant: rows (w>>1)*64 of A, cols (w&1)*64 of B
    const int rh = w >> 1, ch = w & 1;
    // B fragment global base for (nt, h, p): bbase + nt*4096 + h*2048 + p*1024
    const char* bbase = (const char*)znsw + (size_t)Gj * 32768 + ch * 16384 + l * 16;

    // prefetch h=0 B fragments before the barrier (drain together with A)
    frag32 B[4];
    #pragma unroll
    for (int nt = 0; nt < 4; ++nt) {
        B[nt].x[0] = *(const int4*)(bbase + nt * 4096);
        B[nt].x[1] = *(const int4*)(bbase + nt * 4096 + 1024);
    }

    f32x4 acc[4][4];
    #pragma unroll
    for (int mt = 0; mt < 4; ++mt)
        #pragma unroll
        for (int nt = 0; nt < 4; ++nt)
            acc[mt][nt] = (f32x4){0.f, 0.f, 0.f, 0.f};

    __syncthreads();   // A staged; h=0 B in flight drained here too

    #pragma unroll
    for (int h = 0; h < 2; ++h) {
        if (h == 1) {   // reload same buffer with second K-half (exposed
                        // ~L2 latency once; hidden by 12 waves/CU)
            #pragma unroll
            for (int nt = 0; nt < 4; ++nt) {
                B[nt].x[0] = *(const int4*)(bbase + nt * 4096 + 2048);
                B[nt].x[1] = *(const int4*)(bbase + nt * 4096 + 3072);
            }
        }
        #pragma unroll
        for (int mt = 0; mt < 4; ++mt) {
            frag32 A;   // per-mt LDS read: 8 VGPRs live instead of 32
            const char* ap = (const char*)&pan[(rh * 4 + mt) * 4096 + h * 2048] + l * 16;
            A.x[0] = *(const int4*)(ap);
            A.x[1] = *(const int4*)(ap + 1024);
            #pragma unroll
            for (int nt = 0; nt < 4; ++nt)
                acc[mt][nt] = __builtin_amdgcn_mfma_scale_f32_16x16x128_f8f6f4(
                    A.v, B[nt].v, acc[mt][nt],
                    0, 0,                     // cbsz=0 (fp8 e4m3), blgp=0 (fp8)
                    0, 0x7f7f7f7f,            // scale_a opsel, e8m0 1.0
                    0, 0x7f7f7f7f);           // scale_b opsel, e8m0 1.0
        }
    }

    // ---- wave-local epilogue (C/D layout: col = l&15, row = (l>>4)*4+reg) ----
    const int c = l & 15, q = l >> 4;
    const int rsel = c - 4 * q;
    const bool vld = (rsel >= 0) && (rsel < 4);

    // self/pair diagonals live in quadrants with rh==ch
    if ((Gi == Gj || Gj == Gi + 32) && rh == ch) {
        float dv[4];
        #pragma unroll
        for (int mt = 0; mt < 4; ++mt) {
            float d = acc[mt][mt][0];
            #pragma unroll
            for (int r = 1; r < 4; ++r)
                if (rsel == r) d = acc[mt][mt][r];
            dv[mt] = d;
        }
        if (vld) {
            float* dst = (Gi == Gj) ? selfdot : pairdot;
            #pragma unroll
            for (int mt = 0; mt < 4; ++mt)
                dst[Gi * 128 + rh * 64 + mt * 16 + c] = dv[mt];
        }
    }

    #pragma unroll
    for (int mt = 0; mt < 4; ++mt)
        #pragma unroll
        for (int nt = 0; nt < 4; ++nt)
            #pragma unroll
            for (int r = 0; r < 4; ++r)
                acc[mt][nt][r] = __expf(acc[mt][nt][r] * INV_TAU);

    // row sums (DPP reduce across 16 col lanes) -> P[Gj*2+ch][...]
    float rs[4][4];
    #pragma unroll
    for (int mt = 0; mt < 4; ++mt)
        #pragma unroll
        for (int r = 0; r < 4; ++r)
            rs[mt][r] = red16(acc[mt][0][r] + acc[mt][1][r] + acc[mt][2][r] + acc[mt][3][r]);
    if (c == 0) {
        #pragma unroll
        for (int mt = 0; mt < 4; ++mt) {
            const f32x4 o4 = (f32x4){rs[mt][0], rs[mt][1], rs[mt][2], rs[mt][3]};
            __builtin_nontemporal_store(o4,
                (f32x4*)&P[(size_t)(Gj * 2 + ch) * N_ROWS + Gi * 128 + rh * 64 + mt * 16 + q * 4]);
        }
    }

    // col sums (strictly-upper blocks) -> P[Gi*2+rh][Gj*128 + ch*64 + ...]
    if (Gi != Gj) {
        float cs[4];
        #pragma unroll
        for (int nt = 0; nt < 4; ++nt) {
            float s = 0.f;
            #pragma unroll
            for (int mt = 0; mt < 4; ++mt)
                #pragma unroll
                for (int r = 0; r < 4; ++r)
                    s += acc[mt][nt][r];
            s += __shfl_xor(s, 16);
            s += __shfl_xor(s, 32);
            cs[nt] = s;
        }
        if (q == 0) {
            #pragma unroll
            for (int nt = 0; nt < 4; ++nt)
                __builtin_nontemporal_store(cs[nt],
                    &P[(size_t)(Gi * 2 + rh) * N_ROWS + Gj * 128 + ch * 64 + nt * 16 + c]);
        }
    }
}

// ---------------- Kernel 3: per-row loss (latency-hiding) -------------------
__global__ __launch_bounds__(256) void kfinal(const float* __restrict__ P,
                                              const float* __restrict__ selfdot,
                                              const float* __restrict__ pairdot,
                                              float* __restrict__ out) {
    const int l = threadIdx.x & 63;        // row within block
    const int w = threadIdx.x >> 6;        // strip quarter
    const int row = blockIdx.x * 64 + l;
    float s = 0.f;
    #pragma unroll
    for (int st = 0; st < 32; ++st)
        s += P[(size_t)(w * 32 + st) * N_ROWS + row];
    __shared__ float wsum[4][64];
    wsum[w][l] = s;
    __syncthreads();
    if (w == 0) {
        const float tot = wsum[0][l] + wsum[1][l] + wsum[2][l] + wsum[3][l];
        const float selfe = __expf(selfdot[row] * INV_TAU);
        const float pd    = pairdot[(row < BSZ) ? row : row - BSZ];
        float loss = logf(tot - selfe + EPS_REF) - pd * INV_TAU;
        #pragma unroll
        for (int off = 32; off >= 1; off >>= 1) loss += __shfl_xor(loss, off);
        if (l == 0) atomicAdd(out, loss * (1.0f / (float)N_ROWS));
    }
}

extern "C" void kernel_launch(void* const* d_in, const int* in_sizes, int n_in,
                              void* d_out, int out_size, void* d_ws, size_t ws_size,
                              hipStream_t stream) {
    const float* zi = (const float*)d_in[0];
    const float* zj = (const float*)d_in[1];
    float* out = (float*)d_out;

    char* ws = (char*)d_ws;
    unsigned char* znsw = (unsigned char*)ws;                       // 2 MB
    float* P       = (float*)(ws + 2 * 1024 * 1024);                // 4 MB
    float* selfdot = (float*)(ws + 6 * 1024 * 1024);                // 32 KB
    float* pairdot = (float*)(ws + 6 * 1024 * 1024 + 32 * 1024);    // 16 KB

    knorm <<<N_ROWS / 16, 256, 0, stream>>>(zi, zj, znsw, out);
    kgemm <<<NTILES, 256, 0, stream>>>(znsw, P, selfdot, pairdot);
    kfinal<<<N_ROWS / 64, 256, 0, stream>>>(P, selfdot, pairdot, out);
}